// Round 12
// baseline (222.482 us; speedup 1.0000x reference)
//
#include <hip/hip_runtime.h>
#include <stdint.h>

typedef unsigned short u16;
typedef short bf16x8 __attribute__((ext_vector_type(8)));
typedef float f32x4 __attribute__((ext_vector_type(4)));
typedef float f32x16 __attribute__((ext_vector_type(16)));

// element (row, c) of a [*][32] bf16 LDS tile, XOR-swizzled on col bits 3-4
#define SWG(row, c) ((row)*32 + ((c) ^ ((((row)>>1)&3)<<3)))

__device__ __forceinline__ u16 f2b(float f) {  // fp32 -> bf16 RNE
  uint32_t u = __float_as_uint(f);
  u += 0x7fffu + ((u >> 16) & 1u);
  return (u16)(u >> 16);
}

__device__ __forceinline__ uint32_t cvtpk(float lo, float hi) {
  uint32_t r;
  asm("v_cvt_pk_bf16_f32 %0, %1, %2" : "=v"(r) : "v"(lo), "v"(hi));
  return r;
}

typedef __attribute__((address_space(1))) const uint32_t ga_u32;
typedef __attribute__((address_space(3))) uint32_t ls_u32;
__device__ __forceinline__ void gld_lds16(void* lds, const void* g) {
  __builtin_amdgcn_global_load_lds((ga_u32*)g, (ls_u32*)lds, 16, 0, 0);
}

// ---------------------------------------------------------------- convert (fused)
__global__ __launch_bounds__(256) void cvt_all(const float* __restrict__ x,
                                               const float* __restrict__ wqkv,
                                               const float* __restrict__ wout,
                                               u16* __restrict__ xb,
                                               u16* __restrict__ wqkvb,
                                               u16* __restrict__ woutb) {
  const float cexp = 0.18033688011112042f;  // 0.125 * log2(e)
  const int NX = 2097152, NW = 786432;      // float4 counts: x, wqkv
  const int stride = gridDim.x * 256;
  for (int i = blockIdx.x * 256 + threadIdx.x; i < 3145728; i += stride) {
    const float4* src;
    ushort4* dst;
    float sc = 1.0f;
    if (i < NX) {
      src = (const float4*)x + i; dst = (ushort4*)xb + i;
    } else if (i < NX + NW) {
      int j = i - NX;
      src = (const float4*)wqkv + j; dst = (ushort4*)wqkvb + j;
      if (j < 262144) sc = cexp;  // Wq rows [0,1024) of [3072][1024]
    } else {
      int j = i - NX - NW;
      src = (const float4*)wout + j; dst = (ushort4*)woutb + j;
    }
    float4 v = *src;
    ushort4 o;
    o.x = f2b(v.x * sc); o.y = f2b(v.y * sc); o.z = f2b(v.z * sc); o.w = f2b(v.w * sc);
    *dst = o;
  }
}

// ---------------------------------------------------------------- GEMM C = A * B^T
// 128x128 tile, BK=32, 4 waves, double-buffered LDS, counted vmcnt,
// bijective XCD-aware block swizzle (contiguous chunk per XCD -> A panels L2-hit).
template <int OUT_BF16>
__global__ __launch_bounds__(256) void gemm_bt(const u16* __restrict__ A,
                                               const u16* __restrict__ B,
                                               void* __restrict__ Cout,
                                               int M, int N, int K) {
  __shared__ __align__(16) u16 lA[2][128 * 32];
  __shared__ __align__(16) u16 lB[2][128 * 32];
  const int tid = threadIdx.x;
  const int wave = tid >> 6, lane = tid & 63;
  // XCD swizzle: nwg % 8 == 0 for all our launches -> simple bijective form
  const int gx = gridDim.x;
  const int lin = (int)blockIdx.y * gx + (int)blockIdx.x;
  const int qq = (gx * (int)gridDim.y) >> 3;
  const int id = (lin & 7) * qq + (lin >> 3);
  const int m0 = (id / gx) * 128, n0 = (id % gx) * 128;
  const int wm = (wave >> 1) * 64, wn = (wave & 1) * 64;
  const int col = lane & 15, kg = lane >> 4;

  f32x4 acc[4][4] = {};

  const u16* src = (wave < 2) ? (A + (size_t)m0 * K) : (B + (size_t)n0 * K);
  u16* ldst = (wave < 2) ? lA[0] : lB[0];
  const int wc0 = (wave & 1) * 4;
  int srow[4], scol[4];
#pragma unroll
  for (int c = 0; c < 4; ++c) {
    int wc = wc0 + c;
    int row = wc * 16 + (lane >> 2);
    srow[c] = row;
    scol[c] = ((lane & 3) * 8) ^ (((row >> 1) & 3) << 3);
  }

#define GSTAGE(buf, k0_)                                              \
  {                                                                   \
    _Pragma("unroll") for (int c = 0; c < 4; ++c)                     \
        gld_lds16(ldst + (buf)*4096 + (wc0 + c) * 512,                \
                  src + (size_t)srow[c] * K + (k0_) + scol[c]);       \
  }

  GSTAGE(0, 0);

  const int nit = K >> 5;
  for (int it = 0; it < nit; ++it) {
    const int buf = it & 1;
    if (it + 1 < nit) {
      GSTAGE(buf ^ 1, (it + 1) << 5);
      asm volatile("s_waitcnt vmcnt(4)" ::: "memory");
    } else {
      asm volatile("s_waitcnt vmcnt(0)" ::: "memory");
    }
    __builtin_amdgcn_s_barrier();
    asm volatile("" ::: "memory");

    bf16x8 a[4], b[4];
#pragma unroll
    for (int f = 0; f < 4; ++f) {
      a[f] = *(const bf16x8*)(lA[0] + buf * 4096 + SWG(wm + f * 16 + col, kg * 8));
      b[f] = *(const bf16x8*)(lB[0] + buf * 4096 + SWG(wn + f * 16 + col, kg * 8));
    }
#pragma unroll
    for (int i = 0; i < 4; ++i)
#pragma unroll
      for (int j = 0; j < 4; ++j)
        acc[i][j] = __builtin_amdgcn_mfma_f32_16x16x32_bf16(a[i], b[j], acc[i][j], 0, 0, 0);

    asm volatile("" ::: "memory");
    __builtin_amdgcn_s_barrier();  // reads of buf done before it is restaged
  }
#undef GSTAGE

#pragma unroll
  for (int i = 0; i < 4; ++i)
#pragma unroll
    for (int j = 0; j < 4; ++j)
#pragma unroll
      for (int r = 0; r < 4; ++r) {
        int rr = m0 + wm + i * 16 + kg * 4 + r;
        int cc = n0 + wn + j * 16 + col;
        if (OUT_BF16)
          ((u16*)Cout)[(size_t)rr * N + cc] = f2b(acc[i][j][r]);
        else
          ((float*)Cout)[(size_t)rr * N + cc] = acc[i][j][r];
      }
}

// ---------------------------------------------------------------- V transpose
__global__ __launch_bounds__(256) void transpose_v(const u16* __restrict__ qkv,
                                                   u16* __restrict__ vt) {
  __shared__ u16 t[64][65];
  const int bh = blockIdx.y, b = bh >> 4, h = bh & 15;
  const int st = blockIdx.x;
  const u16* src = qkv + (size_t)(b * 4096 + st * 64) * 3072 + 2048 + h * 64;
  for (int c = threadIdx.x; c < 512; c += 256) {
    int r = c >> 3, cc = (c & 7) * 8;
    int4 v = *(const int4*)(src + (size_t)r * 3072 + cc);
    u16* tp = (u16*)&v;
#pragma unroll
    for (int j = 0; j < 8; ++j) t[r][cc + j] = tp[j];
  }
  __syncthreads();
  u16* dst = vt + (size_t)bh * 64 * 4096 + st * 64;
  for (int c = threadIdx.x; c < 512; c += 256) {
    int dh_ = c >> 3, r8 = (c & 7) * 8;
    int4 v;
    u16* tp = (u16*)&v;
#pragma unroll
    for (int j = 0; j < 8; ++j) tp[j] = t[r8 + j][dh_];
    *(int4*)(dst + (size_t)dh_ * 4096 + r8) = v;
  }
}

// ---------------------------------------------------------------- flash attention
// v9 structure + in-lane row-sum: the mfma(P,ones) pair is replaced by a
// 16-wide tree sum of the in-lane P values (lane q=c32 holds 16 of 32 kv per
// chunk; hi-halves partition). lsum accumulates per-lane across tiles; one
// shfl_xor(32) + 512B LDS broadcast redistributes l to the O D-layout at the
// epilogue. Removes 4 of 20 MFMAs per 64-kv tile (-20% matrix-pipe work).
__global__ __launch_bounds__(256, 4) void flash_attn(const u16* __restrict__ qkv,
                                                     const u16* __restrict__ vt,
                                                     u16* __restrict__ attn) {
  __shared__ __align__(16) u16 lds[16384];  // 32KB: K[2][4096] | V[2][4096]@+8192
  __shared__ float l_lds[128];              // per-wave 32 row-sums
  const int bh = blockIdx.x;
  const int b = bh >> 4, h = bh & 15;
  const int qt = 31 - (int)blockIdx.y;  // heavy tiles dispatch first
  const int tid = threadIdx.x;
  const int wave = tid >> 6, lane = tid & 63;
  const int c32 = lane & 31, hi = lane >> 5;

  const u16* kbase = qkv + (size_t)(b * 4096) * 3072 + 1024 + h * 64;
  const u16* vbase = vt + (size_t)bh * (64 * 4096);

#define SWZ(r) (((r) ^ ((r) >> 3)) & 7)
  const int srow0 = wave * 16 + (lane >> 3);
  const int srow1 = srow0 + 8;
  const int cs0 = ((lane & 7) * 8) ^ (SWZ(srow0) << 3);
  const int cs1 = ((lane & 7) * 8) ^ (SWZ(srow1) << 3);
  const int koff0 = srow0 * 3072 + cs0, koff1 = srow1 * 3072 + cs1;
  const int voff0 = srow0 * 4096 + cs0, voff1 = srow1 * 4096 + cs1;

#define STAGE(buf, kp, vp)                                                  \
  {                                                                         \
    gld_lds16(lds + (buf)*4096 + (wave * 2 + 0) * 512, (kp) + koff0);       \
    gld_lds16(lds + (buf)*4096 + (wave * 2 + 1) * 512, (kp) + koff1);       \
    gld_lds16(lds + 8192 + (buf)*4096 + (wave * 2 + 0) * 512, (vp) + voff0);\
    gld_lds16(lds + 8192 + (buf)*4096 + (wave * 2 + 1) * 512, (vp) + voff1);\
  }

  // Q fragments straight to registers (B-operand: col=q, k = s*16+hi*8+j)
  const int qg = qt * 128 + wave * 32 + c32;  // this lane's q row
  bf16x8 qB[4];
  {
    const u16* qrow = qkv + (size_t)(b * 4096 + qg) * 3072 + h * 64 + hi * 8;
#pragma unroll
    for (int s = 0; s < 4; ++s) qB[s] = *(const bf16x8*)(qrow + s * 16);
  }

  STAGE(0, kbase, vbase);

  // loop-invariant fragment-read element offsets (row c32; +2048 elems = +32 rows)
  const int s0sw = SWZ(c32) << 3;
  int va[4], vb[4];
#pragma unroll
  for (int s = 0; s < 4; ++s) {
    int colA = (s * 16 + hi * 8) ^ s0sw;
    va[s] = c32 * 64 + colA;         // rows 0-31 slice, col variant A
    vb[s] = c32 * 64 + (colA ^ 32);  // col variant B (rows 32-63 pair with +2048)
  }

  f32x16 o0 = {}, o1 = {};
  float lsum = 0.f;

#define COMPUTE(CB, jt_)                                                       \
  {                                                                            \
    _Pragma("unroll") for (int c = 0; c < 2; ++c) {                            \
      f32x16 s2 = {};                                                          \
      _Pragma("unroll") for (int s = 0; s < 4; ++s) {                          \
        bf16x8 kf = *(const bf16x8*)(lds + (CB) + c * 2048 +                   \
                                     (c ? vb[s] : va[s]));                     \
        s2 = __builtin_amdgcn_mfma_f32_32x32x16_bf16(kf, qB[s], s2, 0, 0, 0);  \
      }                                                                        \
      if ((jt_) >= 2 * qt) {                                                   \
        const int base = (jt_)*64 + c * 32;                                    \
        _Pragma("unroll") for (int r = 0; r < 16; ++r) {                       \
          const int kvg = base + (r & 3) + 8 * (r >> 2) + 4 * hi;              \
          if (kvg > qg) s2[r] = -1e30f;                                        \
        }                                                                      \
      }                                                                        \
      _Pragma("unroll") for (int r = 0; r < 16; ++r)                           \
          s2[r] = __builtin_amdgcn_exp2f(s2[r]);                               \
      /* in-lane row-sum: this lane's 16 kv values of its own q row */         \
      lsum += ((s2[0] + s2[1]) + (s2[2] + s2[3])) +                            \
              ((s2[4] + s2[5]) + (s2[6] + s2[7])) +                            \
              ((s2[8] + s2[9]) + (s2[10] + s2[11])) +                          \
              ((s2[12] + s2[13]) + (s2[14] + s2[15]));                         \
      uint32_t w0 = cvtpk(s2[0], s2[1]), w1 = cvtpk(s2[2], s2[3]);             \
      uint32_t w2 = cvtpk(s2[4], s2[5]), w3 = cvtpk(s2[6], s2[7]);             \
      uint32_t w4 = cvtpk(s2[8], s2[9]), w5 = cvtpk(s2[10], s2[11]);           \
      uint32_t w6 = cvtpk(s2[12], s2[13]), w7 = cvtpk(s2[14], s2[15]);         \
      asm("v_permlane32_swap_b32 %0, %1" : "+v"(w0), "+v"(w2));                \
      asm("v_permlane32_swap_b32 %0, %1" : "+v"(w1), "+v"(w3));                \
      asm("v_permlane32_swap_b32 %0, %1" : "+v"(w4), "+v"(w6));                \
      asm("v_permlane32_swap_b32 %0, %1" : "+v"(w5), "+v"(w7));                \
      _Pragma("unroll") for (int sub = 0; sub < 2; ++sub) {                    \
        union { uint32_t u[4]; bf16x8 v; } pa;                                 \
        pa.u[0] = sub ? w4 : w0;                                               \
        pa.u[1] = sub ? w5 : w1;                                               \
        pa.u[2] = sub ? w6 : w2;                                               \
        pa.u[3] = sub ? w7 : w3;                                               \
        const int i = c * 2 + sub;                                             \
        bf16x8 vf0 = *(const bf16x8*)(lds + 8192 + (CB) + va[i]);              \
        bf16x8 vf1 = *(const bf16x8*)(lds + 8192 + (CB) + 2048 + vb[i]);       \
        o0 = __builtin_amdgcn_mfma_f32_32x32x16_bf16(pa.v, vf0, o0, 0, 0, 0);  \
        o1 = __builtin_amdgcn_mfma_f32_32x32x16_bf16(pa.v, vf1, o1, 0, 0, 0);  \
      }                                                                        \
    }                                                                          \
  }

  const int nt = 2 * qt + 2;  // always even
  for (int t = 0; t < nt; t += 2) {
    // half A: compute tile t from buf0, prefetch tile t+1 into buf1
    STAGE(1, kbase + (size_t)(t + 1) * (64 * 3072), vbase + (t + 1) * 64);
    asm volatile("s_waitcnt vmcnt(4)" ::: "memory");
    __builtin_amdgcn_s_barrier();
    asm volatile("" ::: "memory");
    COMPUTE(0, t);
    asm volatile("" ::: "memory");
    __builtin_amdgcn_s_barrier();
    // half B: compute tile t+1 from buf1, prefetch tile t+2 into buf0
    if (t + 2 < nt) {
      STAGE(0, kbase + (size_t)(t + 2) * (64 * 3072), vbase + (t + 2) * 64);
      asm volatile("s_waitcnt vmcnt(4)" ::: "memory");
    } else {
      asm volatile("s_waitcnt vmcnt(0)" ::: "memory");
    }
    __builtin_amdgcn_s_barrier();
    asm volatile("" ::: "memory");
    COMPUTE(4096, t + 1);
    asm volatile("" ::: "memory");
    __builtin_amdgcn_s_barrier();
  }
#undef COMPUTE
#undef STAGE

  // complete each q's sum (partner hi-half holds the other 16 kv nibbles),
  // then broadcast via LDS into the O D-layout indexing.
  lsum += __shfl_xor(lsum, 32);
  l_lds[wave * 32 + c32] = lsum;  // both hi-halves write identical value
  asm volatile("s_waitcnt lgkmcnt(0)" ::: "memory");
  __builtin_amdgcn_sched_barrier(0);

  // epilogue: lane holds O rows q = band + (r&3)+8*(r>>2)+4*hi, dh = {c32, 32+c32}
  u16* ob = attn + (size_t)(b * 4096 + qt * 128 + wave * 32) * 1024 + h * 64 + c32;
#pragma unroll
  for (int r = 0; r < 16; ++r) {
    const int ql = (r & 3) + 8 * (r >> 2) + 4 * hi;
    const float rl = __builtin_amdgcn_rcpf(l_lds[wave * 32 + ql]);  // LDS broadcast
    ob[(size_t)ql * 1024] = f2b(o0[r] * rl);
    ob[(size_t)ql * 1024 + 32] = f2b(o1[r] * rl);
  }
}

// ---------------------------------------------------------------- launch
extern "C" void kernel_launch(void* const* d_in, const int* in_sizes, int n_in,
                              void* d_out, int out_size, void* d_ws, size_t ws_size,
                              hipStream_t stream) {
  const float* x = (const float*)d_in[0];
  const float* wqkv = (const float*)d_in[1];
  const float* wout = (const float*)d_in[2];
  float* out = (float*)d_out;

  u16* xb    = (u16*)d_ws;
  u16* wqkvb = xb + (size_t)8192 * 1024;
  u16* woutb = wqkvb + (size_t)3072 * 1024;
  u16* qkvb  = woutb + (size_t)1024 * 1024;
  u16* vtb   = qkvb + (size_t)8192 * 3072;
  u16* attnb = vtb + (size_t)32 * 64 * 4096;

  cvt_all<<<2048, 256, 0, stream>>>(x, wqkv, wout, xb, wqkvb, woutb);

  gemm_bt<1><<<dim3(24, 64), 256, 0, stream>>>(xb, wqkvb, qkvb, 8192, 3072, 1024);
  transpose_v<<<dim3(64, 32), 256, 0, stream>>>(qkvb, vtb);
  flash_attn<<<dim3(32, 32), 256, 0, stream>>>(qkvb, vtb, attnb);
  gemm_bt<0><<<dim3(8, 64), 256, 0, stream>>>(attnb, woutb, out, 8192, 1024, 1024);
}

// Round 13
// 196.357 us; speedup vs baseline: 1.1331x; 1.1331x over previous
//
#include <hip/hip_runtime.h>
#include <stdint.h>

typedef unsigned short u16;
typedef short bf16x8 __attribute__((ext_vector_type(8)));
typedef float f32x4 __attribute__((ext_vector_type(4)));
typedef float f32x16 __attribute__((ext_vector_type(16)));

// element (row, c) of a [*][32] bf16 LDS tile, XOR-swizzled on col bits 3-4
#define SWG(row, c) ((row)*32 + ((c) ^ ((((row)>>1)&3)<<3)))

__device__ __forceinline__ u16 f2b(float f) {  // fp32 -> bf16 RNE
  uint32_t u = __float_as_uint(f);
  u += 0x7fffu + ((u >> 16) & 1u);
  return (u16)(u >> 16);
}

__device__ __forceinline__ uint32_t cvtpk(float lo, float hi) {
  uint32_t r;
  asm("v_cvt_pk_bf16_f32 %0, %1, %2" : "=v"(r) : "v"(lo), "v"(hi));
  return r;
}

typedef __attribute__((address_space(1))) const uint32_t ga_u32;
typedef __attribute__((address_space(3))) uint32_t ls_u32;
__device__ __forceinline__ void gld_lds16(void* lds, const void* g) {
  __builtin_amdgcn_global_load_lds((ga_u32*)g, (ls_u32*)lds, 16, 0, 0);
}

// ---------------------------------------------------------------- convert (fused)
__global__ __launch_bounds__(256) void cvt_all(const float* __restrict__ x,
                                               const float* __restrict__ wqkv,
                                               const float* __restrict__ wout,
                                               u16* __restrict__ xb,
                                               u16* __restrict__ wqkvb,
                                               u16* __restrict__ woutb) {
  const float cexp = 0.18033688011112042f;  // 0.125 * log2(e)
  const int NX = 2097152, NW = 786432;      // float4 counts: x, wqkv
  const int stride = gridDim.x * 256;
  for (int i = blockIdx.x * 256 + threadIdx.x; i < 3145728; i += stride) {
    const float4* src;
    ushort4* dst;
    float sc = 1.0f;
    if (i < NX) {
      src = (const float4*)x + i; dst = (ushort4*)xb + i;
    } else if (i < NX + NW) {
      int j = i - NX;
      src = (const float4*)wqkv + j; dst = (ushort4*)wqkvb + j;
      if (j < 262144) sc = cexp;  // Wq rows [0,1024) of [3072][1024]
    } else {
      int j = i - NX - NW;
      src = (const float4*)wout + j; dst = (ushort4*)woutb + j;
    }
    float4 v = *src;
    ushort4 o;
    o.x = f2b(v.x * sc); o.y = f2b(v.y * sc); o.z = f2b(v.z * sc); o.w = f2b(v.w * sc);
    *dst = o;
  }
}

// ---------------------------------------------------------------- GEMM C = A * B^T
// 128x128 tile, BK=32, 4 waves, double-buffered LDS, counted vmcnt,
// bijective XCD-aware block swizzle (kept from r12: measured ~+9us overall).
template <int OUT_BF16>
__global__ __launch_bounds__(256) void gemm_bt(const u16* __restrict__ A,
                                               const u16* __restrict__ B,
                                               void* __restrict__ Cout,
                                               int M, int N, int K) {
  __shared__ __align__(16) u16 lA[2][128 * 32];
  __shared__ __align__(16) u16 lB[2][128 * 32];
  const int tid = threadIdx.x;
  const int wave = tid >> 6, lane = tid & 63;
  // XCD swizzle: nwg % 8 == 0 for all our launches -> simple bijective form
  const int gx = gridDim.x;
  const int lin = (int)blockIdx.y * gx + (int)blockIdx.x;
  const int qq = (gx * (int)gridDim.y) >> 3;
  const int id = (lin & 7) * qq + (lin >> 3);
  const int m0 = (id / gx) * 128, n0 = (id % gx) * 128;
  const int wm = (wave >> 1) * 64, wn = (wave & 1) * 64;
  const int col = lane & 15, kg = lane >> 4;

  f32x4 acc[4][4] = {};

  const u16* src = (wave < 2) ? (A + (size_t)m0 * K) : (B + (size_t)n0 * K);
  u16* ldst = (wave < 2) ? lA[0] : lB[0];
  const int wc0 = (wave & 1) * 4;
  int srow[4], scol[4];
#pragma unroll
  for (int c = 0; c < 4; ++c) {
    int wc = wc0 + c;
    int row = wc * 16 + (lane >> 2);
    srow[c] = row;
    scol[c] = ((lane & 3) * 8) ^ (((row >> 1) & 3) << 3);
  }

#define GSTAGE(buf, k0_)                                              \
  {                                                                   \
    _Pragma("unroll") for (int c = 0; c < 4; ++c)                     \
        gld_lds16(ldst + (buf)*4096 + (wc0 + c) * 512,                \
                  src + (size_t)srow[c] * K + (k0_) + scol[c]);       \
  }

  GSTAGE(0, 0);

  const int nit = K >> 5;
  for (int it = 0; it < nit; ++it) {
    const int buf = it & 1;
    if (it + 1 < nit) {
      GSTAGE(buf ^ 1, (it + 1) << 5);
      asm volatile("s_waitcnt vmcnt(4)" ::: "memory");
    } else {
      asm volatile("s_waitcnt vmcnt(0)" ::: "memory");
    }
    __builtin_amdgcn_s_barrier();
    asm volatile("" ::: "memory");

    bf16x8 a[4], b[4];
#pragma unroll
    for (int f = 0; f < 4; ++f) {
      a[f] = *(const bf16x8*)(lA[0] + buf * 4096 + SWG(wm + f * 16 + col, kg * 8));
      b[f] = *(const bf16x8*)(lB[0] + buf * 4096 + SWG(wn + f * 16 + col, kg * 8));
    }
#pragma unroll
    for (int i = 0; i < 4; ++i)
#pragma unroll
      for (int j = 0; j < 4; ++j)
        acc[i][j] = __builtin_amdgcn_mfma_f32_16x16x32_bf16(a[i], b[j], acc[i][j], 0, 0, 0);

    asm volatile("" ::: "memory");
    __builtin_amdgcn_s_barrier();  // reads of buf done before it is restaged
  }
#undef GSTAGE

#pragma unroll
  for (int i = 0; i < 4; ++i)
#pragma unroll
    for (int j = 0; j < 4; ++j)
#pragma unroll
      for (int r = 0; r < 4; ++r) {
        int rr = m0 + wm + i * 16 + kg * 4 + r;
        int cc = n0 + wn + j * 16 + col;
        if (OUT_BF16)
          ((u16*)Cout)[(size_t)rr * N + cc] = f2b(acc[i][j][r]);
        else
          ((float*)Cout)[(size_t)rr * N + cc] = acc[i][j][r];
      }
}

// ---------------------------------------------------------------- V transpose
__global__ __launch_bounds__(256) void transpose_v(const u16* __restrict__ qkv,
                                                   u16* __restrict__ vt) {
  __shared__ u16 t[64][65];
  const int bh = blockIdx.y, b = bh >> 4, h = bh & 15;
  const int st = blockIdx.x;
  const u16* src = qkv + (size_t)(b * 4096 + st * 64) * 3072 + 2048 + h * 64;
  for (int c = threadIdx.x; c < 512; c += 256) {
    int r = c >> 3, cc = (c & 7) * 8;
    int4 v = *(const int4*)(src + (size_t)r * 3072 + cc);
    u16* tp = (u16*)&v;
#pragma unroll
    for (int j = 0; j < 8; ++j) t[r][cc + j] = tp[j];
  }
  __syncthreads();
  u16* dst = vt + (size_t)bh * 64 * 4096 + st * 64;
  for (int c = threadIdx.x; c < 512; c += 256) {
    int dh_ = c >> 3, r8 = (c & 7) * 8;
    int4 v;
    u16* tp = (u16*)&v;
#pragma unroll
    for (int j = 0; j < 8; ++j) tp[j] = t[r8 + j][dh_];
    *(int4*)(dst + (size_t)dh_ * 4096 + r8) = v;
  }
}

// ---------------------------------------------------------------- flash attention
// r11-exact version (replay-validated 86.3us, MfmaUtil 46%): swapped 32x32,
// permlane repack, static dbuf addresses, conflict-free SWZ, row-sum via
// mfma(P,ones) (keeps l in the accumulator domain -- r12's in-lane tree sum
// spilled to scratch: WRITE_SIZE +13MB, MfmaUtil 46->24, flash 86->121us).
__global__ __launch_bounds__(256, 4) void flash_attn(const u16* __restrict__ qkv,
                                                     const u16* __restrict__ vt,
                                                     u16* __restrict__ attn) {
  __shared__ __align__(16) u16 lds[16384];  // 32KB: K[2][4096] | V[2][4096]@+8192
  const int bh = blockIdx.x;
  const int b = bh >> 4, h = bh & 15;
  const int qt = 31 - (int)blockIdx.y;  // heavy tiles dispatch first
  const int tid = threadIdx.x;
  const int wave = tid >> 6, lane = tid & 63;
  const int c32 = lane & 31, hi = lane >> 5;

  const u16* kbase = qkv + (size_t)(b * 4096) * 3072 + 1024 + h * 64;
  const u16* vbase = vt + (size_t)bh * (64 * 4096);

#define SWZ(r) (((r) ^ ((r) >> 3)) & 7)
  const int srow0 = wave * 16 + (lane >> 3);
  const int srow1 = srow0 + 8;
  const int cs0 = ((lane & 7) * 8) ^ (SWZ(srow0) << 3);
  const int cs1 = ((lane & 7) * 8) ^ (SWZ(srow1) << 3);
  const int koff0 = srow0 * 3072 + cs0, koff1 = srow1 * 3072 + cs1;
  const int voff0 = srow0 * 4096 + cs0, voff1 = srow1 * 4096 + cs1;

#define STAGE(buf, kp, vp)                                                  \
  {                                                                         \
    gld_lds16(lds + (buf)*4096 + (wave * 2 + 0) * 512, (kp) + koff0);       \
    gld_lds16(lds + (buf)*4096 + (wave * 2 + 1) * 512, (kp) + koff1);       \
    gld_lds16(lds + 8192 + (buf)*4096 + (wave * 2 + 0) * 512, (vp) + voff0);\
    gld_lds16(lds + 8192 + (buf)*4096 + (wave * 2 + 1) * 512, (vp) + voff1);\
  }

  // Q fragments straight to registers (B-operand: col=q, k = s*16+hi*8+j)
  const int qg = qt * 128 + wave * 32 + c32;  // this lane's q row
  bf16x8 qB[4];
  {
    const u16* qrow = qkv + (size_t)(b * 4096 + qg) * 3072 + h * 64 + hi * 8;
#pragma unroll
    for (int s = 0; s < 4; ++s) qB[s] = *(const bf16x8*)(qrow + s * 16);
  }

  STAGE(0, kbase, vbase);

  // loop-invariant fragment-read element offsets (row c32; +2048 elems = +32 rows)
  const int s0sw = SWZ(c32) << 3;
  int va[4], vb[4];
#pragma unroll
  for (int s = 0; s < 4; ++s) {
    int colA = (s * 16 + hi * 8) ^ s0sw;
    va[s] = c32 * 64 + colA;         // rows 0-31 slice, col variant A
    vb[s] = c32 * 64 + (colA ^ 32);  // col variant B (rows 32-63 pair with +2048)
  }

  bf16x8 ones;
#pragma unroll
  for (int j = 0; j < 8; ++j) ones[j] = (short)0x3F80;  // bf16 1.0

  f32x16 o0 = {}, o1 = {}, l_acc = {};

#define COMPUTE(CB, jt_)                                                       \
  {                                                                            \
    _Pragma("unroll") for (int c = 0; c < 2; ++c) {                            \
      f32x16 s2 = {};                                                          \
      _Pragma("unroll") for (int s = 0; s < 4; ++s) {                          \
        bf16x8 kf = *(const bf16x8*)(lds + (CB) + c * 2048 +                   \
                                     (c ? vb[s] : va[s]));                     \
        s2 = __builtin_amdgcn_mfma_f32_32x32x16_bf16(kf, qB[s], s2, 0, 0, 0);  \
      }                                                                        \
      if ((jt_) >= 2 * qt) {                                                   \
        const int base = (jt_)*64 + c * 32;                                    \
        _Pragma("unroll") for (int r = 0; r < 16; ++r) {                       \
          const int kvg = base + (r & 3) + 8 * (r >> 2) + 4 * hi;              \
          if (kvg > qg) s2[r] = -1e30f;                                        \
        }                                                                      \
      }                                                                        \
      _Pragma("unroll") for (int r = 0; r < 16; ++r)                           \
          s2[r] = __builtin_amdgcn_exp2f(s2[r]);                               \
      uint32_t w0 = cvtpk(s2[0], s2[1]), w1 = cvtpk(s2[2], s2[3]);             \
      uint32_t w2 = cvtpk(s2[4], s2[5]), w3 = cvtpk(s2[6], s2[7]);             \
      uint32_t w4 = cvtpk(s2[8], s2[9]), w5 = cvtpk(s2[10], s2[11]);           \
      uint32_t w6 = cvtpk(s2[12], s2[13]), w7 = cvtpk(s2[14], s2[15]);         \
      asm("v_permlane32_swap_b32 %0, %1" : "+v"(w0), "+v"(w2));                \
      asm("v_permlane32_swap_b32 %0, %1" : "+v"(w1), "+v"(w3));                \
      asm("v_permlane32_swap_b32 %0, %1" : "+v"(w4), "+v"(w6));                \
      asm("v_permlane32_swap_b32 %0, %1" : "+v"(w5), "+v"(w7));                \
      _Pragma("unroll") for (int sub = 0; sub < 2; ++sub) {                    \
        union { uint32_t u[4]; bf16x8 v; } pa;                                 \
        pa.u[0] = sub ? w4 : w0;                                               \
        pa.u[1] = sub ? w5 : w1;                                               \
        pa.u[2] = sub ? w6 : w2;                                               \
        pa.u[3] = sub ? w7 : w3;                                               \
        const int i = c * 2 + sub;                                             \
        bf16x8 vf0 = *(const bf16x8*)(lds + 8192 + (CB) + va[i]);              \
        bf16x8 vf1 = *(const bf16x8*)(lds + 8192 + (CB) + 2048 + vb[i]);       \
        l_acc = __builtin_amdgcn_mfma_f32_32x32x16_bf16(pa.v, ones, l_acc, 0, 0, 0); \
        o0 = __builtin_amdgcn_mfma_f32_32x32x16_bf16(pa.v, vf0, o0, 0, 0, 0);  \
        o1 = __builtin_amdgcn_mfma_f32_32x32x16_bf16(pa.v, vf1, o1, 0, 0, 0);  \
      }                                                                        \
    }                                                                          \
  }

  const int nt = 2 * qt + 2;  // always even
  for (int t = 0; t < nt; t += 2) {
    // half A: compute tile t from buf0, prefetch tile t+1 into buf1
    STAGE(1, kbase + (size_t)(t + 1) * (64 * 3072), vbase + (t + 1) * 64);
    asm volatile("s_waitcnt vmcnt(4)" ::: "memory");
    __builtin_amdgcn_s_barrier();
    asm volatile("" ::: "memory");
    COMPUTE(0, t);
    asm volatile("" ::: "memory");
    __builtin_amdgcn_s_barrier();
    // half B: compute tile t+1 from buf1, prefetch tile t+2 into buf0
    if (t + 2 < nt) {
      STAGE(0, kbase + (size_t)(t + 2) * (64 * 3072), vbase + (t + 2) * 64);
      asm volatile("s_waitcnt vmcnt(4)" ::: "memory");
    } else {
      asm volatile("s_waitcnt vmcnt(0)" ::: "memory");
    }
    __builtin_amdgcn_s_barrier();
    asm volatile("" ::: "memory");
    COMPUTE(4096, t + 1);
    asm volatile("" ::: "memory");
    __builtin_amdgcn_s_barrier();
  }
#undef COMPUTE
#undef STAGE

  // epilogue: lane holds O rows q = band + (r&3)+8*(r>>2)+4*hi, dh = {c32, 32+c32}
  u16* ob = attn + (size_t)(b * 4096 + qt * 128 + wave * 32) * 1024 + h * 64 + c32;
#pragma unroll
  for (int r = 0; r < 16; ++r) {
    const int ql = (r & 3) + 8 * (r >> 2) + 4 * hi;
    const float rl = __builtin_amdgcn_rcpf(l_acc[r]);
    ob[(size_t)ql * 1024] = f2b(o0[r] * rl);
    ob[(size_t)ql * 1024 + 32] = f2b(o1[r] * rl);
  }
}

// ---------------------------------------------------------------- launch
extern "C" void kernel_launch(void* const* d_in, const int* in_sizes, int n_in,
                              void* d_out, int out_size, void* d_ws, size_t ws_size,
                              hipStream_t stream) {
  const float* x = (const float*)d_in[0];
  const float* wqkv = (const float*)d_in[1];
  const float* wout = (const float*)d_in[2];
  float* out = (float*)d_out;

  u16* xb    = (u16*)d_ws;
  u16* wqkvb = xb + (size_t)8192 * 1024;
  u16* woutb = wqkvb + (size_t)3072 * 1024;
  u16* qkvb  = woutb + (size_t)1024 * 1024;
  u16* vtb   = qkvb + (size_t)8192 * 3072;
  u16* attnb = vtb + (size_t)32 * 64 * 4096;

  cvt_all<<<2048, 256, 0, stream>>>(x, wqkv, wout, xb, wqkvb, woutb);

  gemm_bt<1><<<dim3(24, 64), 256, 0, stream>>>(xb, wqkvb, qkvb, 8192, 3072, 1024);
  transpose_v<<<dim3(64, 32), 256, 0, stream>>>(qkvb, vtb);
  flash_attn<<<dim3(32, 32), 256, 0, stream>>>(qkvb, vtb, attnb);
  gemm_bt<0><<<dim3(8, 64), 256, 0, stream>>>(attnb, woutb, out, 8192, 1024, 1024);
}

// Round 14
// 193.539 us; speedup vs baseline: 1.1496x; 1.0146x over previous
//
#include <hip/hip_runtime.h>
#include <stdint.h>

typedef unsigned short u16;
typedef short bf16x8 __attribute__((ext_vector_type(8)));
typedef float f32x4 __attribute__((ext_vector_type(4)));
typedef float f32x16 __attribute__((ext_vector_type(16)));

// element (row, c) of a [*][32] bf16 LDS tile, XOR-swizzled on col bits 3-4
#define SWG(row, c) ((row)*32 + ((c) ^ ((((row)>>1)&3)<<3)))

__device__ __forceinline__ u16 f2b(float f) {  // fp32 -> bf16 RNE
  uint32_t u = __float_as_uint(f);
  u += 0x7fffu + ((u >> 16) & 1u);
  return (u16)(u >> 16);
}

__device__ __forceinline__ uint32_t cvtpk(float lo, float hi) {
  uint32_t r;
  asm("v_cvt_pk_bf16_f32 %0, %1, %2" : "=v"(r) : "v"(lo), "v"(hi));
  return r;
}

typedef __attribute__((address_space(1))) const uint32_t ga_u32;
typedef __attribute__((address_space(3))) uint32_t ls_u32;
__device__ __forceinline__ void gld_lds16(void* lds, const void* g) {
  __builtin_amdgcn_global_load_lds((ga_u32*)g, (ls_u32*)lds, 16, 0, 0);
}

// ---------------------------------------------------------------- convert (fused)
__global__ __launch_bounds__(256) void cvt_all(const float* __restrict__ x,
                                               const float* __restrict__ wqkv,
                                               const float* __restrict__ wout,
                                               u16* __restrict__ xb,
                                               u16* __restrict__ wqkvb,
                                               u16* __restrict__ woutb) {
  const float cexp = 0.18033688011112042f;  // 0.125 * log2(e)
  const int NX = 2097152, NW = 786432;      // float4 counts: x, wqkv
  const int stride = gridDim.x * 256;
  for (int i = blockIdx.x * 256 + threadIdx.x; i < 3145728; i += stride) {
    const float4* src;
    ushort4* dst;
    float sc = 1.0f;
    if (i < NX) {
      src = (const float4*)x + i; dst = (ushort4*)xb + i;
    } else if (i < NX + NW) {
      int j = i - NX;
      src = (const float4*)wqkv + j; dst = (ushort4*)wqkvb + j;
      if (j < 262144) sc = cexp;  // Wq rows [0,1024) of [3072][1024]
    } else {
      int j = i - NX - NW;
      src = (const float4*)wout + j; dst = (ushort4*)woutb + j;
    }
    float4 v = *src;
    ushort4 o;
    o.x = f2b(v.x * sc); o.y = f2b(v.y * sc); o.z = f2b(v.z * sc); o.w = f2b(v.w * sc);
    *dst = o;
  }
}

// ---------------------------------------------------------------- GEMM C = A * B^T
// 128x128 tile, BK=32, 4 waves, double-buffered LDS, counted vmcnt, XCD swizzle.
// V_SPLIT (gemm1): blocks with n0>=2048 own the V panel (boundary 2048 is a
// multiple of BN) and write it DIRECTLY TRANSPOSED to vt[bh][dh][s] -- this
// replaces the separate transpose_v kernel (saves a 32MB round trip).
template <int OUT_BF16, int V_SPLIT>
__global__ __launch_bounds__(256) void gemm_bt(const u16* __restrict__ A,
                                               const u16* __restrict__ B,
                                               void* __restrict__ Cout,
                                               u16* __restrict__ Vt,
                                               int M, int N, int K) {
  __shared__ __align__(16) u16 lA[2][128 * 32];
  __shared__ __align__(16) u16 lB[2][128 * 32];
  const int tid = threadIdx.x;
  const int wave = tid >> 6, lane = tid & 63;
  // XCD swizzle: nwg % 8 == 0 for all our launches -> simple bijective form
  const int gx = gridDim.x;
  const int lin = (int)blockIdx.y * gx + (int)blockIdx.x;
  const int qq = (gx * (int)gridDim.y) >> 3;
  const int id = (lin & 7) * qq + (lin >> 3);
  const int m0 = (id / gx) * 128, n0 = (id % gx) * 128;
  const int wm = (wave >> 1) * 64, wn = (wave & 1) * 64;
  const int col = lane & 15, kg = lane >> 4;

  f32x4 acc[4][4] = {};

  const u16* src = (wave < 2) ? (A + (size_t)m0 * K) : (B + (size_t)n0 * K);
  u16* ldst = (wave < 2) ? lA[0] : lB[0];
  const int wc0 = (wave & 1) * 4;
  int srow[4], scol[4];
#pragma unroll
  for (int c = 0; c < 4; ++c) {
    int wc = wc0 + c;
    int row = wc * 16 + (lane >> 2);
    srow[c] = row;
    scol[c] = ((lane & 3) * 8) ^ (((row >> 1) & 3) << 3);
  }

#define GSTAGE(buf, k0_)                                              \
  {                                                                   \
    _Pragma("unroll") for (int c = 0; c < 4; ++c)                     \
        gld_lds16(ldst + (buf)*4096 + (wc0 + c) * 512,                \
                  src + (size_t)srow[c] * K + (k0_) + scol[c]);       \
  }

  GSTAGE(0, 0);

  const int nit = K >> 5;
  for (int it = 0; it < nit; ++it) {
    const int buf = it & 1;
    if (it + 1 < nit) {
      GSTAGE(buf ^ 1, (it + 1) << 5);
      asm volatile("s_waitcnt vmcnt(4)" ::: "memory");
    } else {
      asm volatile("s_waitcnt vmcnt(0)" ::: "memory");
    }
    __builtin_amdgcn_s_barrier();
    asm volatile("" ::: "memory");

    bf16x8 a[4], b[4];
#pragma unroll
    for (int f = 0; f < 4; ++f) {
      a[f] = *(const bf16x8*)(lA[0] + buf * 4096 + SWG(wm + f * 16 + col, kg * 8));
      b[f] = *(const bf16x8*)(lB[0] + buf * 4096 + SWG(wn + f * 16 + col, kg * 8));
    }
#pragma unroll
    for (int i = 0; i < 4; ++i)
#pragma unroll
      for (int j = 0; j < 4; ++j)
        acc[i][j] = __builtin_amdgcn_mfma_f32_16x16x32_bf16(a[i], b[j], acc[i][j], 0, 0, 0);

    asm volatile("" ::: "memory");
    __builtin_amdgcn_s_barrier();  // reads of buf done before it is restaged
  }
#undef GSTAGE

  if (V_SPLIT && n0 >= 2048) {
    // V panel: write transposed vt[bh][dh][s];  bh = (m0>>12)*16 + head,
    // dh = wn-local col (j*16+col fits in [0,64)), s = row within batch.
    u16* vb0 = Vt + ((size_t)(m0 >> 12) * 16 + ((n0 - 2048 + wn) >> 6)) * 262144
               + (m0 & 4095) + wm + kg * 4;
#pragma unroll
    for (int i = 0; i < 4; ++i)
#pragma unroll
      for (int j = 0; j < 4; ++j)
#pragma unroll
        for (int r = 0; r < 4; ++r)
          vb0[(size_t)(j * 16 + col) * 4096 + i * 16 + r] = f2b(acc[i][j][r]);
    return;
  }

#pragma unroll
  for (int i = 0; i < 4; ++i)
#pragma unroll
    for (int j = 0; j < 4; ++j)
#pragma unroll
      for (int r = 0; r < 4; ++r) {
        int rr = m0 + wm + i * 16 + kg * 4 + r;
        int cc = n0 + wn + j * 16 + col;
        if (OUT_BF16)
          ((u16*)Cout)[(size_t)rr * N + cc] = f2b(acc[i][j][r]);
        else
          ((float*)Cout)[(size_t)rr * N + cc] = acc[i][j][r];
      }
}

// ---------------------------------------------------------------- flash attention
// r11-exact version (replay-validated 86.3us, MfmaUtil 46%): swapped 32x32,
// permlane repack, static dbuf addresses, conflict-free SWZ, row-sum via
// mfma(P,ones) (keeps l in the accumulator domain).
__global__ __launch_bounds__(256, 4) void flash_attn(const u16* __restrict__ qkv,
                                                     const u16* __restrict__ vt,
                                                     u16* __restrict__ attn) {
  __shared__ __align__(16) u16 lds[16384];  // 32KB: K[2][4096] | V[2][4096]@+8192
  const int bh = blockIdx.x;
  const int b = bh >> 4, h = bh & 15;
  const int qt = 31 - (int)blockIdx.y;  // heavy tiles dispatch first
  const int tid = threadIdx.x;
  const int wave = tid >> 6, lane = tid & 63;
  const int c32 = lane & 31, hi = lane >> 5;

  const u16* kbase = qkv + (size_t)(b * 4096) * 3072 + 1024 + h * 64;
  const u16* vbase = vt + (size_t)bh * (64 * 4096);

#define SWZ(r) (((r) ^ ((r) >> 3)) & 7)
  const int srow0 = wave * 16 + (lane >> 3);
  const int srow1 = srow0 + 8;
  const int cs0 = ((lane & 7) * 8) ^ (SWZ(srow0) << 3);
  const int cs1 = ((lane & 7) * 8) ^ (SWZ(srow1) << 3);
  const int koff0 = srow0 * 3072 + cs0, koff1 = srow1 * 3072 + cs1;
  const int voff0 = srow0 * 4096 + cs0, voff1 = srow1 * 4096 + cs1;

#define STAGE(buf, kp, vp)                                                  \
  {                                                                         \
    gld_lds16(lds + (buf)*4096 + (wave * 2 + 0) * 512, (kp) + koff0);       \
    gld_lds16(lds + (buf)*4096 + (wave * 2 + 1) * 512, (kp) + koff1);       \
    gld_lds16(lds + 8192 + (buf)*4096 + (wave * 2 + 0) * 512, (vp) + voff0);\
    gld_lds16(lds + 8192 + (buf)*4096 + (wave * 2 + 1) * 512, (vp) + voff1);\
  }

  // Q fragments straight to registers (B-operand: col=q, k = s*16+hi*8+j)
  const int qg = qt * 128 + wave * 32 + c32;  // this lane's q row
  bf16x8 qB[4];
  {
    const u16* qrow = qkv + (size_t)(b * 4096 + qg) * 3072 + h * 64 + hi * 8;
#pragma unroll
    for (int s = 0; s < 4; ++s) qB[s] = *(const bf16x8*)(qrow + s * 16);
  }

  STAGE(0, kbase, vbase);

  // loop-invariant fragment-read element offsets (row c32; +2048 elems = +32 rows)
  const int s0sw = SWZ(c32) << 3;
  int va[4], vb[4];
#pragma unroll
  for (int s = 0; s < 4; ++s) {
    int colA = (s * 16 + hi * 8) ^ s0sw;
    va[s] = c32 * 64 + colA;         // rows 0-31 slice, col variant A
    vb[s] = c32 * 64 + (colA ^ 32);  // col variant B (rows 32-63 pair with +2048)
  }

  bf16x8 ones;
#pragma unroll
  for (int j = 0; j < 8; ++j) ones[j] = (short)0x3F80;  // bf16 1.0

  f32x16 o0 = {}, o1 = {}, l_acc = {};

#define COMPUTE(CB, jt_)                                                       \
  {                                                                            \
    _Pragma("unroll") for (int c = 0; c < 2; ++c) {                            \
      f32x16 s2 = {};                                                          \
      _Pragma("unroll") for (int s = 0; s < 4; ++s) {                          \
        bf16x8 kf = *(const bf16x8*)(lds + (CB) + c * 2048 +                   \
                                     (c ? vb[s] : va[s]));                     \
        s2 = __builtin_amdgcn_mfma_f32_32x32x16_bf16(kf, qB[s], s2, 0, 0, 0);  \
      }                                                                        \
      if ((jt_) >= 2 * qt) {                                                   \
        const int base = (jt_)*64 + c * 32;                                    \
        _Pragma("unroll") for (int r = 0; r < 16; ++r) {                       \
          const int kvg = base + (r & 3) + 8 * (r >> 2) + 4 * hi;              \
          if (kvg > qg) s2[r] = -1e30f;                                        \
        }                                                                      \
      }                                                                        \
      _Pragma("unroll") for (int r = 0; r < 16; ++r)                           \
          s2[r] = __builtin_amdgcn_exp2f(s2[r]);                               \
      uint32_t w0 = cvtpk(s2[0], s2[1]), w1 = cvtpk(s2[2], s2[3]);             \
      uint32_t w2 = cvtpk(s2[4], s2[5]), w3 = cvtpk(s2[6], s2[7]);             \
      uint32_t w4 = cvtpk(s2[8], s2[9]), w5 = cvtpk(s2[10], s2[11]);           \
      uint32_t w6 = cvtpk(s2[12], s2[13]), w7 = cvtpk(s2[14], s2[15]);         \
      asm("v_permlane32_swap_b32 %0, %1" : "+v"(w0), "+v"(w2));                \
      asm("v_permlane32_swap_b32 %0, %1" : "+v"(w1), "+v"(w3));                \
      asm("v_permlane32_swap_b32 %0, %1" : "+v"(w4), "+v"(w6));                \
      asm("v_permlane32_swap_b32 %0, %1" : "+v"(w5), "+v"(w7));                \
      _Pragma("unroll") for (int sub = 0; sub < 2; ++sub) {                    \
        union { uint32_t u[4]; bf16x8 v; } pa;                                 \
        pa.u[0] = sub ? w4 : w0;                                               \
        pa.u[1] = sub ? w5 : w1;                                               \
        pa.u[2] = sub ? w6 : w2;                                               \
        pa.u[3] = sub ? w7 : w3;                                               \
        const int i = c * 2 + sub;                                             \
        bf16x8 vf0 = *(const bf16x8*)(lds + 8192 + (CB) + va[i]);              \
        bf16x8 vf1 = *(const bf16x8*)(lds + 8192 + (CB) + 2048 + vb[i]);       \
        l_acc = __builtin_amdgcn_mfma_f32_32x32x16_bf16(pa.v, ones, l_acc, 0, 0, 0); \
        o0 = __builtin_amdgcn_mfma_f32_32x32x16_bf16(pa.v, vf0, o0, 0, 0, 0);  \
        o1 = __builtin_amdgcn_mfma_f32_32x32x16_bf16(pa.v, vf1, o1, 0, 0, 0);  \
      }                                                                        \
    }                                                                          \
  }

  const int nt = 2 * qt + 2;  // always even
  for (int t = 0; t < nt; t += 2) {
    // half A: compute tile t from buf0, prefetch tile t+1 into buf1
    STAGE(1, kbase + (size_t)(t + 1) * (64 * 3072), vbase + (t + 1) * 64);
    asm volatile("s_waitcnt vmcnt(4)" ::: "memory");
    __builtin_amdgcn_s_barrier();
    asm volatile("" ::: "memory");
    COMPUTE(0, t);
    asm volatile("" ::: "memory");
    __builtin_amdgcn_s_barrier();
    // half B: compute tile t+1 from buf1, prefetch tile t+2 into buf0
    if (t + 2 < nt) {
      STAGE(0, kbase + (size_t)(t + 2) * (64 * 3072), vbase + (t + 2) * 64);
      asm volatile("s_waitcnt vmcnt(4)" ::: "memory");
    } else {
      asm volatile("s_waitcnt vmcnt(0)" ::: "memory");
    }
    __builtin_amdgcn_s_barrier();
    asm volatile("" ::: "memory");
    COMPUTE(4096, t + 1);
    asm volatile("" ::: "memory");
    __builtin_amdgcn_s_barrier();
  }
#undef COMPUTE
#undef STAGE

  // epilogue: lane holds O rows q = band + (r&3)+8*(r>>2)+4*hi, dh = {c32, 32+c32}
  u16* ob = attn + (size_t)(b * 4096 + qt * 128 + wave * 32) * 1024 + h * 64 + c32;
#pragma unroll
  for (int r = 0; r < 16; ++r) {
    const int ql = (r & 3) + 8 * (r >> 2) + 4 * hi;
    const float rl = __builtin_amdgcn_rcpf(l_acc[r]);
    ob[(size_t)ql * 1024] = f2b(o0[r] * rl);
    ob[(size_t)ql * 1024 + 32] = f2b(o1[r] * rl);
  }
}

// ---------------------------------------------------------------- launch
extern "C" void kernel_launch(void* const* d_in, const int* in_sizes, int n_in,
                              void* d_out, int out_size, void* d_ws, size_t ws_size,
                              hipStream_t stream) {
  const float* x = (const float*)d_in[0];
  const float* wqkv = (const float*)d_in[1];
  const float* wout = (const float*)d_in[2];
  float* out = (float*)d_out;

  u16* xb    = (u16*)d_ws;
  u16* wqkvb = xb + (size_t)8192 * 1024;
  u16* woutb = wqkvb + (size_t)3072 * 1024;
  u16* qkvb  = woutb + (size_t)1024 * 1024;
  u16* vtb   = qkvb + (size_t)8192 * 3072;
  u16* attnb = vtb + (size_t)32 * 64 * 4096;

  cvt_all<<<2048, 256, 0, stream>>>(x, wqkv, wout, xb, wqkvb, woutb);

  gemm_bt<1, 1><<<dim3(24, 64), 256, 0, stream>>>(xb, wqkvb, qkvb, vtb,
                                                  8192, 3072, 1024);
  flash_attn<<<dim3(32, 32), 256, 0, stream>>>(qkvb, vtb, attnb);
  gemm_bt<0, 0><<<dim3(8, 64), 256, 0, stream>>>(attnb, woutb, out, nullptr,
                                                 8192, 1024, 1024);
}